// Round 1
// baseline (615.717 us; speedup 1.0000x reference)
//
#include <hip/hip_runtime.h>
#include <hip/hip_fp16.h>

#define N_NODES 20000
#define N_EDGES 320000
#define DIM 256
// H=8 heads, C=32 channels/head

typedef _Float16 f16;
typedef f16 f16x8 __attribute__((ext_vector_type(8)));
typedef f16 f16x4 __attribute__((ext_vector_type(4)));
typedef float f32x4 __attribute__((ext_vector_type(4)));

// ---- prep: W (K=256 x N=256, f32 row-major) -> WT (N x K, f16) ----
__global__ void prep_wt(const float* __restrict__ W, f16* __restrict__ WT) {
    int idx = blockIdx.x * blockDim.x + threadIdx.x; // 65536 total
    int k = idx >> 8, n = idx & 255;
    WT[n * 256 + k] = (f16)W[k * 256 + n];
}

// ---- GEMM: out[M x 256] = A[M x 256] @ W + bias ----
// WT is W transposed (N x K) in f16. Block = 256 thr = 4 waves; block tile = 128 rows.
// Each wave: 2 row-tiles of 16 x full 256 cols (16 col-tiles), K-loop 8 steps of 32.
// MFMA A/B fragments use identical k-mapping (k = kstep*32 + (lane>>4)*8 + e), which is
// correct for any internal HW k-layout (sum over k is permutation invariant).
// C/D layout (HW-verified): col = lane&15, row = (lane>>4)*4 + reg.
template<int STORE_F16>
__global__ __launch_bounds__(256, 2) void gemm256(
    const float* __restrict__ A, const f16* __restrict__ WT,
    const float* __restrict__ bias, void* __restrict__ out, int M)
{
    const int wave = threadIdx.x >> 6;
    const int lane = threadIdx.x & 63;
    const int l16 = lane & 15;
    const int lg  = lane >> 4;
    const int rowBase = blockIdx.x * 128 + wave * 32;

    f32x4 acc[2][16];
#pragma unroll
    for (int r = 0; r < 2; ++r)
#pragma unroll
        for (int c = 0; c < 16; ++c) acc[r][c] = (f32x4){0.f, 0.f, 0.f, 0.f};

    for (int ks = 0; ks < 8; ++ks) {
        const int k0 = ks * 32 + lg * 8;
        f16x8 a[2];
#pragma unroll
        for (int r = 0; r < 2; ++r) {
            int row = rowBase + r * 16 + l16;
            if (row >= M) row = M - 1;   // clamp (guarded at store)
            const float* ap = A + (long)row * DIM + k0;
            f32x4 lo = *(const f32x4*)ap;
            f32x4 hi = *(const f32x4*)(ap + 4);
            f16x8 av;
#pragma unroll
            for (int j = 0; j < 4; ++j) { av[j] = (f16)lo[j]; av[4 + j] = (f16)hi[j]; }
            a[r] = av;
        }
#pragma unroll
        for (int ct = 0; ct < 16; ++ct) {
            f16x8 b = *(const f16x8*)(WT + (ct * 16 + l16) * 256 + k0);
            acc[0][ct] = __builtin_amdgcn_mfma_f32_16x16x32_f16(a[0], b, acc[0][ct], 0, 0, 0);
            acc[1][ct] = __builtin_amdgcn_mfma_f32_16x16x32_f16(a[1], b, acc[1][ct], 0, 0, 0);
        }
    }
#pragma unroll
    for (int r = 0; r < 2; ++r) {
#pragma unroll
        for (int ct = 0; ct < 16; ++ct) {
            const int col = ct * 16 + l16;
            const float bv = bias ? bias[col] : 0.f;
#pragma unroll
            for (int i = 0; i < 4; ++i) {
                int row = rowBase + r * 16 + lg * 4 + i;
                if (row < M) {
                    float val = acc[r][ct][i] + bv;
                    if (STORE_F16) ((f16*)out)[(long)row * 256 + col] = (f16)val;
                    else           ((float*)out)[(long)row * 256 + col] = val;
                }
            }
        }
    }
}

// ---- CSR build (by dst) ----
__global__ void count_deg(const int* __restrict__ dst, int* __restrict__ deg) {
    int e = blockIdx.x * blockDim.x + threadIdx.x;
    if (e < N_EDGES) atomicAdd(&deg[dst[e]], 1);
}

__global__ __launch_bounds__(1024) void scan_deg(const int* __restrict__ deg,
                                                 int* __restrict__ rowptr,
                                                 int* __restrict__ cursor) {
    __shared__ int part[1024];
    const int t = threadIdx.x;
    const int CH = (N_NODES + 1023) / 1024; // 20
    const int base = t * CH;
    int s = 0;
    for (int i = 0; i < CH; ++i) { int n = base + i; if (n < N_NODES) s += deg[n]; }
    part[t] = s;
    __syncthreads();
    for (int off = 1; off < 1024; off <<= 1) {
        int v = (t >= off) ? part[t - off] : 0;
        __syncthreads();
        part[t] += v;
        __syncthreads();
    }
    int run = (t == 0) ? 0 : part[t - 1];
    for (int i = 0; i < CH; ++i) {
        int n = base + i;
        if (n < N_NODES) { int dn = deg[n]; rowptr[n] = run; cursor[n] = run; run += dn; }
    }
    if (t == 1023) rowptr[N_NODES] = part[1023]; // == E
}

__global__ void scatter_edges(const int* __restrict__ dst, int* __restrict__ cursor,
                              int* __restrict__ eids) {
    int e = blockIdx.x * blockDim.x + threadIdx.x;
    if (e < N_EDGES) { int p = atomicAdd(&cursor[dst[e]], 1); eids[p] = e; }
}

// ---- fused softmax + aggregate: one wave per dst node ----
// lane l handles channels [4l, 4l+4); head h = l/8 spans lanes [8h, 8h+8).
__global__ __launch_bounds__(256) void aggregate(
    const f16* __restrict__ qf, const f16* __restrict__ kf, const f16* __restrict__ vf,
    const f16* __restrict__ ef, const int* __restrict__ srcArr,
    const int* __restrict__ rowptr, const int* __restrict__ eids,
    float* __restrict__ out)
{
    const int wave = threadIdx.x >> 6;
    const int lane = threadIdx.x & 63;
    const int node = blockIdx.x * 4 + wave;
    if (node >= N_NODES) return;
    const int c0 = lane * 4;

    f32x4 qv;
    {
        f16x4 qh = *(const f16x4*)(qf + (long)node * 256 + c0);
        qv = (f32x4){(float)qh[0], (float)qh[1], (float)qh[2], (float)qh[3]};
    }
    float acc0 = 0.f, acc1 = 0.f, acc2 = 0.f, acc3 = 0.f, den = 0.f;
    const int beg = rowptr[node], end = rowptr[node + 1];
    for (int idx = beg; idx < end; ++idx) {
        const int eid = eids[idx];
        const int src = srcArr[eid];
        f16x4 eh = *(const f16x4*)(ef + (long)eid * 256 + c0);
        f16x4 kh = *(const f16x4*)(kf + (long)src * 256 + c0);
        f16x4 vh = *(const f16x4*)(vf + (long)src * 256 + c0);
        const float e0 = (float)eh[0], e1 = (float)eh[1], e2 = (float)eh[2], e3 = (float)eh[3];
        float d = qv[0] * ((float)kh[0] + e0) + qv[1] * ((float)kh[1] + e1)
                + qv[2] * ((float)kh[2] + e2) + qv[3] * ((float)kh[3] + e3);
        d += __shfl_xor(d, 1);
        d += __shfl_xor(d, 2);
        d += __shfl_xor(d, 4);                  // full 32-channel dot within head
        const float ea = __expf(d * 0.1767766952966369f); // 1/sqrt(32)
        den += ea;
        acc0 += ea * ((float)vh[0] + e0);
        acc1 += ea * ((float)vh[1] + e1);
        acc2 += ea * ((float)vh[2] + e2);
        acc3 += ea * ((float)vh[3] + e3);
    }
    const float inv = 1.0f / (den + 1e-16f);
    const long ob = (long)node * 256 + c0;
    f32x4 o = *(f32x4*)(out + ob);              // holds skip from gemm256<0>
    o[0] += acc0 * inv; o[1] += acc1 * inv; o[2] += acc2 * inv; o[3] += acc3 * inv;
    *(f32x4*)(out + ob) = o;
}

extern "C" void kernel_launch(void* const* d_in, const int* in_sizes, int n_in,
                              void* d_out, int out_size, void* d_ws, size_t ws_size,
                              hipStream_t stream) {
    const float* x   = (const float*)d_in[0];
    const int*   ei  = (const int*)d_in[1];     // [0..E): src, [E..2E): dst
    const float* ea  = (const float*)d_in[2];
    const float* Wq  = (const float*)d_in[3];
    const float* bq  = (const float*)d_in[4];
    const float* Wk  = (const float*)d_in[5];
    const float* bk  = (const float*)d_in[6];
    const float* Wv  = (const float*)d_in[7];
    const float* bv  = (const float*)d_in[8];
    const float* We  = (const float*)d_in[9];
    const float* Ws  = (const float*)d_in[10];
    const float* bs  = (const float*)d_in[11];
    float* out = (float*)d_out;

    const int* srcArr = ei;
    const int* dstArr = ei + N_EDGES;

    // workspace layout
    char* w = (char*)d_ws;
    size_t off = 0;
    f16* wt[5];
    for (int i = 0; i < 5; ++i) { wt[i] = (f16*)(w + off); off += 256 * 256 * 2; } // q,k,v,s,e
    f16* qf = (f16*)(w + off); off += (size_t)N_NODES * 256 * 2;
    f16* kf = (f16*)(w + off); off += (size_t)N_NODES * 256 * 2;
    f16* vf = (f16*)(w + off); off += (size_t)N_NODES * 256 * 2;
    f16* ef = (f16*)(w + off); off += (size_t)N_EDGES * 256 * 2;
    int* deg    = (int*)(w + off); off += 80016;
    int* rowptr = (int*)(w + off); off += 80016;
    int* cursor = (int*)(w + off); off += 80016;
    int* eids   = (int*)(w + off); off += (size_t)N_EDGES * 4;
    (void)ws_size; (void)n_in; (void)in_sizes; (void)out_size;

    // weights -> f16 transposed
    prep_wt<<<256, 256, 0, stream>>>(Wq, wt[0]);
    prep_wt<<<256, 256, 0, stream>>>(Wk, wt[1]);
    prep_wt<<<256, 256, 0, stream>>>(Wv, wt[2]);
    prep_wt<<<256, 256, 0, stream>>>(Ws, wt[3]);
    prep_wt<<<256, 256, 0, stream>>>(We, wt[4]);

    // CSR build (independent of GEMMs)
    hipMemsetAsync(deg, 0, N_NODES * 4, stream);
    count_deg<<<(N_EDGES + 255) / 256, 256, 0, stream>>>(dstArr, deg);
    scan_deg<<<1, 1024, 0, stream>>>(deg, rowptr, cursor);
    scatter_edges<<<(N_EDGES + 255) / 256, 256, 0, stream>>>(dstArr, cursor, eids);

    // GEMMs
    const int nb_node = (N_NODES + 127) / 128;   // 157
    const int nb_edge = N_EDGES / 128;           // 2500
    gemm256<1><<<nb_node, 256, 0, stream>>>(x, wt[0], bq, qf, N_NODES);
    gemm256<1><<<nb_node, 256, 0, stream>>>(x, wt[1], bk, kf, N_NODES);
    gemm256<1><<<nb_node, 256, 0, stream>>>(x, wt[2], bv, vf, N_NODES);
    gemm256<0><<<nb_node, 256, 0, stream>>>(x, wt[3], bs, (void*)out, N_NODES);
    gemm256<1><<<nb_edge, 256, 0, stream>>>(ea, wt[4], nullptr, ef, N_EDGES);

    // fused softmax + aggregation, one wave per node
    aggregate<<<N_NODES / 4, 256, 0, stream>>>(qf, kf, vf, ef, srcArr, rowptr, eids, out);
}

// Round 2
// 391.766 us; speedup vs baseline: 1.5716x; 1.5716x over previous
//
#include <hip/hip_runtime.h>
#include <hip/hip_fp16.h>

#define N_NODES 20000
#define N_EDGES 320000
#define DIM 256
// H=8 heads, C=32 channels/head

typedef _Float16 f16;
typedef unsigned int u32;
typedef f16 f16x8 __attribute__((ext_vector_type(8)));
typedef f16 f16x4 __attribute__((ext_vector_type(4)));
typedef float f32x4 __attribute__((ext_vector_type(4)));

#define GLL16(gsrc, ldst) __builtin_amdgcn_global_load_lds( \
    (const u32 __attribute__((address_space(1)))*)(gsrc),   \
    (u32 __attribute__((address_space(3)))*)(ldst), 16, 0, 0)

// ---- prep: 5 weights f32 (K x N) -> f16 transposed (N x K), + pack 4 biases ----
__global__ void prep_all(const float* __restrict__ Wq, const float* __restrict__ Wk,
                         const float* __restrict__ Wv, const float* __restrict__ Ws,
                         const float* __restrict__ We,
                         const float* __restrict__ bq, const float* __restrict__ bk,
                         const float* __restrict__ bv, const float* __restrict__ bs,
                         f16* __restrict__ wtbase, float* __restrict__ biasAll) {
    if (blockIdx.x < 1280) {
        int gid = blockIdx.x * 256 + threadIdx.x;
        int w = gid >> 16;            // 0..4 : q,k,v,s,e
        int idx = gid & 65535;
        int k = idx >> 8, n = idx & 255;
        const float* W = (w == 0) ? Wq : (w == 1) ? Wk : (w == 2) ? Wv : (w == 3) ? Ws : We;
        wtbase[w * 65536 + n * 256 + k] = (f16)W[k * 256 + n];
    } else {
        int i = (blockIdx.x - 1280) * 256 + threadIdx.x;  // 0..1023
        if (i < 1024) {
            int y = i >> 8, col = i & 255;
            const float* b = (y == 0) ? bq : (y == 1) ? bk : (y == 2) ? bv : bs;
            biasAll[i] = b[col];
        }
    }
}

// ---- GEMM v2: out[M x 256] = A[M x 256] @ W (+bias) ----
// Block 256 thr = 4 waves. Block tile 64 rows x 256 cols; wave tile 32x128.
// B (WT, N-major x K) staged per-K-step in LDS via global_load_lds, double-buffered.
// A direct HBM->reg, prefetched one K-step ahead. K-loop fully unrolled, 1 barrier/step.
// EDGE=1: single output f16 (ef). EDGE=0: blockIdx.y in 0..3 -> q,k,v (f16) / skip (f32).
template<int EDGE>
__global__ __launch_bounds__(256, 2) void gemm_v2(
    const float* __restrict__ A, const f16* __restrict__ WTbase,
    const float* __restrict__ biasAll,
    f16* __restrict__ outF16, float* __restrict__ outF32, int M)
{
    __shared__ __align__(16) char ldsB[2][16384];   // [buf][n*64 + kchunk*16]
    const int tid = threadIdx.x;
    const int wave = tid >> 6, lane = tid & 63;
    const int l16 = lane & 15, lg = lane >> 4;
    const int rowBase = blockIdx.x * 64 + (wave & 1) * 32;
    const int colBase = (wave >> 1) * 128;
    const int y = EDGE ? 0 : blockIdx.y;
    const f16* __restrict__ WT = WTbase + (EDGE ? 4 * 65536 : y * 65536);

    // stage B tile for k-step ks into buffer b: 256 n x 32 k x f16 = 16 KB
    auto STAGE = [&](int b, int ks) {
#pragma unroll
        for (int i = 0; i < 4; ++i) {
            const int r = wave * 4 + i;                    // 1 KB region, n in [r*16, r*16+16)
            const int n = r * 16 + (lane >> 2);
            const int kc = lane & 3;
            const f16* src = WT + n * 256 + ks * 32 + kc * 8;
            GLL16(src, &ldsB[b][r * 1024]);                // lane writes base + lane*16
        }
    };

    f32x4 a_lo[2], a_hi[2];
    auto LOADA = [&](int ks) {
#pragma unroll
        for (int m = 0; m < 2; ++m) {
            int row = rowBase + m * 16 + l16;
            if (row >= M) row = M - 1;                     // clamp; stores guarded
            const float* ap = A + (size_t)row * DIM + ks * 32 + lg * 8;
            a_lo[m] = *(const f32x4*)ap;
            a_hi[m] = *(const f32x4*)(ap + 4);
        }
    };

    f32x4 acc[2][8];
#pragma unroll
    for (int m = 0; m < 2; ++m)
#pragma unroll
        for (int c = 0; c < 8; ++c) acc[m][c] = (f32x4){0.f, 0.f, 0.f, 0.f};

    STAGE(0, 0);
    LOADA(0);

#pragma unroll
    for (int ks = 0; ks < 8; ++ks) {
        __syncthreads();               // drains stage(ks) + A(ks) loads; orders LDS reuse
        if (ks < 7) STAGE((ks + 1) & 1, ks + 1);   // overlaps with this step's compute
        f16x8 afr[2];
#pragma unroll
        for (int m = 0; m < 2; ++m) {
#pragma unroll
            for (int j = 0; j < 4; ++j) {
                afr[m][j]     = (f16)a_lo[m][j];
                afr[m][4 + j] = (f16)a_hi[m][j];
            }
        }
        if (ks < 7) LOADA(ks + 1);
        const char* bbuf = ldsB[ks & 1];
#pragma unroll
        for (int ct = 0; ct < 8; ++ct) {
            f16x8 b = *(const f16x8*)(bbuf + (colBase + ct * 16 + l16) * 64 + lg * 16);
            acc[0][ct] = __builtin_amdgcn_mfma_f32_16x16x32_f16(afr[0], b, acc[0][ct], 0, 0, 0);
            acc[1][ct] = __builtin_amdgcn_mfma_f32_16x16x32_f16(afr[1], b, acc[1][ct], 0, 0, 0);
        }
    }

    // epilogue: C/D layout col = ct*16 + l16, row = m*16 + lg*4 + i
#pragma unroll
    for (int m = 0; m < 2; ++m) {
#pragma unroll
        for (int ct = 0; ct < 8; ++ct) {
            const int col = colBase + ct * 16 + l16;
            const float bv = EDGE ? 0.f : biasAll[y * 256 + col];
#pragma unroll
            for (int i = 0; i < 4; ++i) {
                const int row = rowBase + m * 16 + lg * 4 + i;
                if (row < M) {
                    const float val = acc[m][ct][i] + bv;
                    if (EDGE) {
                        outF16[(size_t)row * 256 + col] = (f16)val;
                    } else if (y < 3) {
                        (outF16 + (size_t)y * N_NODES * 256)[(size_t)row * 256 + col] = (f16)val;
                    } else {
                        outF32[(size_t)row * 256 + col] = val;
                    }
                }
            }
        }
    }
}

// ---- CSR build (by dst) ----
__global__ void count_deg(const int* __restrict__ dst, int* __restrict__ deg) {
    int e = blockIdx.x * blockDim.x + threadIdx.x;
    if (e < N_EDGES) atomicAdd(&deg[dst[e]], 1);
}

__global__ __launch_bounds__(1024) void scan_deg(const int* __restrict__ deg,
                                                 int* __restrict__ rowptr,
                                                 int* __restrict__ cursor) {
    __shared__ int part[1024];
    const int t = threadIdx.x;
    const int CH = (N_NODES + 1023) / 1024; // 20
    const int base = t * CH;
    int s = 0;
    for (int i = 0; i < CH; ++i) { int n = base + i; if (n < N_NODES) s += deg[n]; }
    part[t] = s;
    __syncthreads();
    for (int off = 1; off < 1024; off <<= 1) {
        int v = (t >= off) ? part[t - off] : 0;
        __syncthreads();
        part[t] += v;
        __syncthreads();
    }
    int run = (t == 0) ? 0 : part[t - 1];
    for (int i = 0; i < CH; ++i) {
        int n = base + i;
        if (n < N_NODES) { int dn = deg[n]; rowptr[n] = run; cursor[n] = run; run += dn; }
    }
    if (t == 1023) rowptr[N_NODES] = part[1023]; // == E
}

__global__ void scatter_edges(const int* __restrict__ dst, int* __restrict__ cursor,
                              int* __restrict__ eids) {
    int e = blockIdx.x * blockDim.x + threadIdx.x;
    if (e < N_EDGES) { int p = atomicAdd(&cursor[dst[e]], 1); eids[p] = e; }
}

// ---- fused softmax + aggregate: one wave per dst node ----
// lane l handles channels [4l, 4l+4); head h = l/8 spans lanes [8h, 8h+8).
__global__ __launch_bounds__(256) void aggregate(
    const f16* __restrict__ qf, const f16* __restrict__ kf, const f16* __restrict__ vf,
    const f16* __restrict__ ef, const int* __restrict__ srcArr,
    const int* __restrict__ rowptr, const int* __restrict__ eids,
    float* __restrict__ out)
{
    const int wave = threadIdx.x >> 6;
    const int lane = threadIdx.x & 63;
    const int node = blockIdx.x * 4 + wave;
    if (node >= N_NODES) return;
    const int c0 = lane * 4;

    f32x4 qv;
    {
        f16x4 qh = *(const f16x4*)(qf + (size_t)node * 256 + c0);
        qv = (f32x4){(float)qh[0], (float)qh[1], (float)qh[2], (float)qh[3]};
    }
    float acc0 = 0.f, acc1 = 0.f, acc2 = 0.f, acc3 = 0.f, den = 0.f;
    const int beg = rowptr[node], end = rowptr[node + 1];
    for (int idx = beg; idx < end; ++idx) {
        const int eid = eids[idx];
        const int src = srcArr[eid];
        f16x4 eh = *(const f16x4*)(ef + (size_t)eid * 256 + c0);
        f16x4 kh = *(const f16x4*)(kf + (size_t)src * 256 + c0);
        f16x4 vh = *(const f16x4*)(vf + (size_t)src * 256 + c0);
        const float e0 = (float)eh[0], e1 = (float)eh[1], e2 = (float)eh[2], e3 = (float)eh[3];
        float d = qv[0] * ((float)kh[0] + e0) + qv[1] * ((float)kh[1] + e1)
                + qv[2] * ((float)kh[2] + e2) + qv[3] * ((float)kh[3] + e3);
        d += __shfl_xor(d, 1);
        d += __shfl_xor(d, 2);
        d += __shfl_xor(d, 4);                  // full 32-channel dot within head
        const float ea = __expf(d * 0.1767766952966369f); // 1/sqrt(32)
        den += ea;
        acc0 += ea * ((float)vh[0] + e0);
        acc1 += ea * ((float)vh[1] + e1);
        acc2 += ea * ((float)vh[2] + e2);
        acc3 += ea * ((float)vh[3] + e3);
    }
    const float inv = 1.0f / (den + 1e-16f);
    const size_t ob = (size_t)node * 256 + c0;
    f32x4 o = *(f32x4*)(out + ob);              // holds skip from gemm_v2 y==3
    o[0] += acc0 * inv; o[1] += acc1 * inv; o[2] += acc2 * inv; o[3] += acc3 * inv;
    *(f32x4*)(out + ob) = o;
}

extern "C" void kernel_launch(void* const* d_in, const int* in_sizes, int n_in,
                              void* d_out, int out_size, void* d_ws, size_t ws_size,
                              hipStream_t stream) {
    const float* x   = (const float*)d_in[0];
    const int*   ei  = (const int*)d_in[1];     // [0..E): src, [E..2E): dst
    const float* ea  = (const float*)d_in[2];
    const float* Wq  = (const float*)d_in[3];
    const float* bq  = (const float*)d_in[4];
    const float* Wk  = (const float*)d_in[5];
    const float* bk  = (const float*)d_in[6];
    const float* Wv  = (const float*)d_in[7];
    const float* bv  = (const float*)d_in[8];
    const float* We  = (const float*)d_in[9];
    const float* Ws  = (const float*)d_in[10];
    const float* bs  = (const float*)d_in[11];
    float* out = (float*)d_out;

    const int* srcArr = ei;
    const int* dstArr = ei + N_EDGES;

    // workspace layout
    char* w = (char*)d_ws;
    size_t off = 0;
    f16* wtbase = (f16*)(w + off); off += 5 * 65536 * 2;            // q,k,v,s,e transposed
    f16* qf = (f16*)(w + off); off += (size_t)N_NODES * 256 * 2;
    f16* kf = (f16*)(w + off); off += (size_t)N_NODES * 256 * 2;
    f16* vf = (f16*)(w + off); off += (size_t)N_NODES * 256 * 2;
    f16* ef = (f16*)(w + off); off += (size_t)N_EDGES * 256 * 2;
    int* deg    = (int*)(w + off); off += 80016;
    int* rowptr = (int*)(w + off); off += 80016;
    int* cursor = (int*)(w + off); off += 80016;
    int* eids   = (int*)(w + off); off += (size_t)N_EDGES * 4;
    float* biasAll = (float*)(w + off); off += 4 * 256 * 4;
    (void)ws_size; (void)n_in; (void)in_sizes; (void)out_size;

    // weights -> f16 transposed + bias pack (one launch)
    prep_all<<<1284, 256, 0, stream>>>(Wq, Wk, Wv, Ws, We, bq, bk, bv, bs, wtbase, biasAll);

    // CSR build (independent of GEMMs)
    hipMemsetAsync(deg, 0, N_NODES * 4, stream);
    count_deg<<<(N_EDGES + 255) / 256, 256, 0, stream>>>(dstArr, deg);
    scan_deg<<<1, 1024, 0, stream>>>(deg, rowptr, cursor);
    scatter_edges<<<(N_EDGES + 255) / 256, 256, 0, stream>>>(dstArr, cursor, eids);

    // GEMMs: node (4 fused via grid.y) + edge
    dim3 gnode((N_NODES + 63) / 64, 4);
    gemm_v2<0><<<gnode, 256, 0, stream>>>(x, wtbase, biasAll, qf, out, N_NODES);
    gemm_v2<1><<<N_EDGES / 64, 256, 0, stream>>>(ea, wtbase, nullptr, ef, nullptr, N_EDGES);

    // fused softmax + aggregation, one wave per node
    aggregate<<<N_NODES / 4, 256, 0, stream>>>(qf, kf, vf, ef, srcArr, rowptr, eids, out);
}

// Round 3
// 385.703 us; speedup vs baseline: 1.5964x; 1.0157x over previous
//
#include <hip/hip_runtime.h>
#include <hip/hip_fp16.h>

#define N_NODES 20000
#define N_EDGES 320000
#define DIM 256
// H=8 heads, C=32 channels/head

typedef _Float16 f16;
typedef unsigned int u32;
typedef f16 f16x8 __attribute__((ext_vector_type(8)));
typedef f16 f16x4 __attribute__((ext_vector_type(4)));
typedef float f32x4 __attribute__((ext_vector_type(4)));

#define GLL16(gsrc, ldst) __builtin_amdgcn_global_load_lds( \
    (const u32 __attribute__((address_space(1)))*)(gsrc),   \
    (u32 __attribute__((address_space(3)))*)(ldst), 16, 0, 0)

// ---- prep: 5 weights f32 (K x N) -> f16 transposed (N x K), + pack 4 biases ----
__global__ void prep_all(const float* __restrict__ Wq, const float* __restrict__ Wk,
                         const float* __restrict__ Wv, const float* __restrict__ Ws,
                         const float* __restrict__ We,
                         const float* __restrict__ bq, const float* __restrict__ bk,
                         const float* __restrict__ bv, const float* __restrict__ bs,
                         f16* __restrict__ wtbase, float* __restrict__ biasAll) {
    if (blockIdx.x < 1280) {
        int gid = blockIdx.x * 256 + threadIdx.x;
        int w = gid >> 16;            // 0..4 : q,k,v,s,e
        int idx = gid & 65535;
        int k = idx >> 8, n = idx & 255;
        const float* W = (w == 0) ? Wq : (w == 1) ? Wk : (w == 2) ? Wv : (w == 3) ? Ws : We;
        wtbase[w * 65536 + n * 256 + k] = (f16)W[k * 256 + n];
    } else {
        int i = (blockIdx.x - 1280) * 256 + threadIdx.x;  // 0..1023
        if (i < 1024) {
            int y = i >> 8, col = i & 255;
            const float* b = (y == 0) ? bq : (y == 1) ? bk : (y == 2) ? bv : bs;
            biasAll[i] = b[col];
        }
    }
}

__global__ void zero_deg(int* __restrict__ deg) {
    int i = blockIdx.x * 256 + threadIdx.x;
    if (i < N_NODES) deg[i] = 0;
}

// ---- GEMM v3: out[M x 256] = A[M x 256] @ W (+bias) ----
// Block 512 thr = 8 waves; block tile 128 rows x 256 cols; wave tile 32x128.
// ALL of B (WT slice, 128 KB f16) staged into LDS once (wave w stages k-step w),
// ONE barrier, then the K-loop has no barriers: A is HBM->reg prefetched depth-3
// (static slot indices via full unroll), B comes from LDS.
// LDS bank swizzle: data for (n, kchunk kc) lives at byte n*64 + (kc ^ ((n>>1)&3))*16
// within its k-step tile; applied as pre-swizzled GLOBAL source on the write side
// (global_load_lds dest must stay linear) and the matching XOR on the ds_read side.
// 16 lanes/group then cover all eight 16B slots twice -> 2-way (free).
template<int EDGE>
__global__ __launch_bounds__(512, 2) void gemm_v3(
    const float* __restrict__ A, const f16* __restrict__ WTbase,
    const float* __restrict__ biasAll,
    f16* __restrict__ outF16, float* __restrict__ outF32, int M)
{
    __shared__ __align__(16) char ldsB[131072];     // 8 k-steps x 16 KB
    const int tid = threadIdx.x;
    const int wave = tid >> 6, lane = tid & 63;
    const int l16 = lane & 15, lg = lane >> 4;
    const int rowBase = blockIdx.x * 128 + (wave & 3) * 32;
    const int colBase = (wave >> 2) * 128;
    const int y = EDGE ? 4 : blockIdx.y;
    const f16* __restrict__ WT = WTbase + y * 65536;

    // stage all of B: wave w -> k-step w (16 regions x 1 KB)
    {
        const int nrel = lane >> 2;                       // row within region
        const int kc = (lane & 3) ^ ((lane >> 3) & 3);    // swizzled k-chunk
        const f16* srcBase = WT + wave * 32 + kc * 8;
#pragma unroll
        for (int r = 0; r < 16; ++r) {
            const f16* src = srcBase + (size_t)(r * 16 + nrel) * 256;
            GLL16(src, &ldsB[wave * 16384 + r * 1024]);   // lane i -> base + i*16
        }
    }

    f32x4 alo[3][2], ahi[3][2];
#define LOADA(ks_, s_) do {                                                   \
    _Pragma("unroll")                                                         \
    for (int m_ = 0; m_ < 2; ++m_) {                                          \
        int row_ = rowBase + m_ * 16 + l16;                                   \
        if (row_ >= M) row_ = M - 1;                                          \
        const float* ap_ = A + (size_t)row_ * DIM + (ks_) * 32 + lg * 8;      \
        alo[s_][m_] = *(const f32x4*)ap_;                                     \
        ahi[s_][m_] = *(const f32x4*)(ap_ + 4);                               \
    } } while (0)

    LOADA(0, 0); LOADA(1, 1); LOADA(2, 2);

    f32x4 acc[2][8];
#pragma unroll
    for (int m = 0; m < 2; ++m)
#pragma unroll
        for (int c = 0; c < 8; ++c) acc[m][c] = (f32x4){0.f, 0.f, 0.f, 0.f};

    const int swzRead = (lg ^ ((l16 >> 1) & 3)) * 16;

    __syncthreads();   // B fully staged (drains A prefetch too, one-time)

#pragma unroll
    for (int ks = 0; ks < 8; ++ks) {
        const int slot = ks % 3;            // constant after full unroll
        f16x8 afr[2];
#pragma unroll
        for (int m = 0; m < 2; ++m) {
#pragma unroll
            for (int j = 0; j < 4; ++j) {
                afr[m][j]     = (f16)alo[slot][m][j];
                afr[m][4 + j] = (f16)ahi[slot][m][j];
            }
        }
        if (ks < 5) LOADA(ks + 3, slot);    // refill consumed slot
        const char* bbuf = ldsB + ks * 16384;
#pragma unroll
        for (int ct = 0; ct < 8; ++ct) {
            const int n = colBase + ct * 16 + l16;
            f16x8 b = *(const f16x8*)(bbuf + n * 64 + swzRead);
            acc[0][ct] = __builtin_amdgcn_mfma_f32_16x16x32_f16(afr[0], b, acc[0][ct], 0, 0, 0);
            acc[1][ct] = __builtin_amdgcn_mfma_f32_16x16x32_f16(afr[1], b, acc[1][ct], 0, 0, 0);
        }
    }
#undef LOADA

    // epilogue: C/D layout col = ct*16 + l16, row = m*16 + lg*4 + i
#pragma unroll
    for (int m = 0; m < 2; ++m) {
#pragma unroll
        for (int ct = 0; ct < 8; ++ct) {
            const int col = colBase + ct * 16 + l16;
            const float bv = EDGE ? 0.f : biasAll[y * 256 + col];
#pragma unroll
            for (int i = 0; i < 4; ++i) {
                const int row = rowBase + m * 16 + lg * 4 + i;
                if (row < M) {
                    const float val = acc[m][ct][i] + bv;
                    if (EDGE) {
                        outF16[(size_t)row * 256 + col] = (f16)val;
                    } else if (y < 3) {
                        (outF16 + (size_t)y * N_NODES * 256)[(size_t)row * 256 + col] = (f16)val;
                    } else {
                        outF32[(size_t)row * 256 + col] = val;
                    }
                }
            }
        }
    }
}

// ---- CSR build (by dst) ----
__global__ void count_deg(const int* __restrict__ dst, int* __restrict__ deg) {
    int e = blockIdx.x * blockDim.x + threadIdx.x;
    if (e < N_EDGES) atomicAdd(&deg[dst[e]], 1);
}

__global__ __launch_bounds__(1024) void scan_deg(const int* __restrict__ deg,
                                                 int* __restrict__ rowptr,
                                                 int* __restrict__ cursor) {
    __shared__ int part[1024];
    const int t = threadIdx.x;
    const int CH = (N_NODES + 1023) / 1024; // 20
    const int base = t * CH;
    int s = 0;
    for (int i = 0; i < CH; ++i) { int n = base + i; if (n < N_NODES) s += deg[n]; }
    part[t] = s;
    __syncthreads();
    for (int off = 1; off < 1024; off <<= 1) {
        int v = (t >= off) ? part[t - off] : 0;
        __syncthreads();
        part[t] += v;
        __syncthreads();
    }
    int run = (t == 0) ? 0 : part[t - 1];
    for (int i = 0; i < CH; ++i) {
        int n = base + i;
        if (n < N_NODES) { int dn = deg[n]; rowptr[n] = run; cursor[n] = run; run += dn; }
    }
    if (t == 1023) rowptr[N_NODES] = part[1023]; // == E
}

__global__ void scatter_edges(const int* __restrict__ dst, int* __restrict__ cursor,
                              int* __restrict__ eids) {
    int e = blockIdx.x * blockDim.x + threadIdx.x;
    if (e < N_EDGES) { int p = atomicAdd(&cursor[dst[e]], 1); eids[p] = e; }
}

// ---- fused softmax + aggregate: one wave per dst node ----
// lane l handles channels [4l, 4l+4); head h = l/8 spans lanes [8h, 8h+8).
__global__ __launch_bounds__(256) void aggregate(
    const f16* __restrict__ qf, const f16* __restrict__ kf, const f16* __restrict__ vf,
    const f16* __restrict__ ef, const int* __restrict__ srcArr,
    const int* __restrict__ rowptr, const int* __restrict__ eids,
    float* __restrict__ out)
{
    const int wave = threadIdx.x >> 6;
    const int lane = threadIdx.x & 63;
    const int node = blockIdx.x * 4 + wave;
    if (node >= N_NODES) return;
    const int c0 = lane * 4;

    f32x4 qv;
    {
        f16x4 qh = *(const f16x4*)(qf + (size_t)node * 256 + c0);
        qv = (f32x4){(float)qh[0], (float)qh[1], (float)qh[2], (float)qh[3]};
    }
    float acc0 = 0.f, acc1 = 0.f, acc2 = 0.f, acc3 = 0.f, den = 0.f;
    const int beg = rowptr[node], end = rowptr[node + 1];
    for (int idx = beg; idx < end; ++idx) {
        const int eid = eids[idx];
        const int src = srcArr[eid];
        f16x4 eh = *(const f16x4*)(ef + (size_t)eid * 256 + c0);
        f16x4 kh = *(const f16x4*)(kf + (size_t)src * 256 + c0);
        f16x4 vh = *(const f16x4*)(vf + (size_t)src * 256 + c0);
        const float e0 = (float)eh[0], e1 = (float)eh[1], e2 = (float)eh[2], e3 = (float)eh[3];
        float d = qv[0] * ((float)kh[0] + e0) + qv[1] * ((float)kh[1] + e1)
                + qv[2] * ((float)kh[2] + e2) + qv[3] * ((float)kh[3] + e3);
        d += __shfl_xor(d, 1);
        d += __shfl_xor(d, 2);
        d += __shfl_xor(d, 4);                  // full 32-channel dot within head
        const float ea = __expf(d * 0.1767766952966369f); // 1/sqrt(32)
        den += ea;
        acc0 += ea * ((float)vh[0] + e0);
        acc1 += ea * ((float)vh[1] + e1);
        acc2 += ea * ((float)vh[2] + e2);
        acc3 += ea * ((float)vh[3] + e3);
    }
    const float inv = 1.0f / (den + 1e-16f);
    const size_t ob = (size_t)node * 256 + c0;
    f32x4 o = *(f32x4*)(out + ob);              // holds skip from gemm_v3 y==3
    o[0] += acc0 * inv; o[1] += acc1 * inv; o[2] += acc2 * inv; o[3] += acc3 * inv;
    *(f32x4*)(out + ob) = o;
}

extern "C" void kernel_launch(void* const* d_in, const int* in_sizes, int n_in,
                              void* d_out, int out_size, void* d_ws, size_t ws_size,
                              hipStream_t stream) {
    const float* x   = (const float*)d_in[0];
    const int*   ei  = (const int*)d_in[1];     // [0..E): src, [E..2E): dst
    const float* ea  = (const float*)d_in[2];
    const float* Wq  = (const float*)d_in[3];
    const float* bq  = (const float*)d_in[4];
    const float* Wk  = (const float*)d_in[5];
    const float* bk  = (const float*)d_in[6];
    const float* Wv  = (const float*)d_in[7];
    const float* bv  = (const float*)d_in[8];
    const float* We  = (const float*)d_in[9];
    const float* Ws  = (const float*)d_in[10];
    const float* bs  = (const float*)d_in[11];
    float* out = (float*)d_out;

    const int* srcArr = ei;
    const int* dstArr = ei + N_EDGES;

    // workspace layout
    char* w = (char*)d_ws;
    size_t off = 0;
    f16* wtbase = (f16*)(w + off); off += 5 * 65536 * 2;            // q,k,v,s,e transposed
    f16* qf = (f16*)(w + off); off += (size_t)N_NODES * 256 * 2;
    f16* kf = (f16*)(w + off); off += (size_t)N_NODES * 256 * 2;
    f16* vf = (f16*)(w + off); off += (size_t)N_NODES * 256 * 2;
    f16* ef = (f16*)(w + off); off += (size_t)N_EDGES * 256 * 2;
    int* deg    = (int*)(w + off); off += 80016;
    int* rowptr = (int*)(w + off); off += 80016;
    int* cursor = (int*)(w + off); off += 80016;
    int* eids   = (int*)(w + off); off += (size_t)N_EDGES * 4;
    float* biasAll = (float*)(w + off); off += 4 * 256 * 4;
    (void)ws_size; (void)n_in; (void)in_sizes; (void)out_size;

    // weights -> f16 transposed + bias pack (one launch)
    prep_all<<<1284, 256, 0, stream>>>(Wq, Wk, Wv, Ws, We, bq, bk, bv, bs, wtbase, biasAll);

    // CSR build (independent of GEMMs)
    zero_deg<<<(N_NODES + 255) / 256, 256, 0, stream>>>(deg);
    count_deg<<<(N_EDGES + 255) / 256, 256, 0, stream>>>(dstArr, deg);
    scan_deg<<<1, 1024, 0, stream>>>(deg, rowptr, cursor);
    scatter_edges<<<(N_EDGES + 255) / 256, 256, 0, stream>>>(dstArr, cursor, eids);

    // GEMMs: node (4 fused via grid.y) + edge
    dim3 gnode((N_NODES + 127) / 128, 4);
    gemm_v3<0><<<gnode, 512, 0, stream>>>(x, wtbase, biasAll, qf, out, N_NODES);
    gemm_v3<1><<<N_EDGES / 128, 512, 0, stream>>>(ea, wtbase, nullptr, ef, nullptr, N_EDGES);

    // fused softmax + aggregation, one wave per node
    aggregate<<<N_NODES / 4, 256, 0, stream>>>(qf, kf, vf, ef, srcArr, rowptr, eids, out);
}